// Round 4
// baseline (1803.945 us; speedup 1.0000x reference)
//
#include <hip/hip_runtime.h>

// B=64,K=64 -> 4096 (b,k) blocks; L=128 rows; D=128; H=256; 6 layers.
// Phase-1 fp32 tiles XOR-swizzled on 16B chunks with FULL 5-bit mask:
// chunk' = chunk ^ (row&31)  -> sim e-loads (32 rows, same chunk) fully bank-spread
#define FID4(r,c4) ((r)*128 + ((((c4) ^ ((r)&31))) << 2))               // float4 chunk addr (dwords)
#define FIDS(r,c)  ((r)*128 + (((((c)>>2) ^ ((r)&31))) << 2) + ((c)&3))  // scalar float addr

typedef __attribute__((ext_vector_type(8))) short bf16x8;
typedef __attribute__((ext_vector_type(4))) float f32x4;

__device__ __forceinline__ unsigned short f2bf(float f){   // RNE float->bf16 bits
    unsigned u = __float_as_uint(f);
    u += 0x7fffu + ((u >> 16) & 1u);
    return (unsigned short)(u >> 16);
}
__device__ __forceinline__ float bf2f(unsigned short b){
    return __uint_as_float(((unsigned)b) << 16);
}
__device__ __forceinline__ float tanh_fast(float x){
    float e = __expf(2.0f * x);
    return 1.0f - 2.0f / (e + 1.0f);
}

// W -> bf16 hi + bf16 lo (w ~= hi + lo; lo holds next 8 mantissa bits)
__global__ void pack_w_kernel(const float* __restrict__ Ws,
                              unsigned short* __restrict__ Wh,
                              unsigned short* __restrict__ Wl){
    int i = blockIdx.x * 256 + threadIdx.x;   // 6*256*256 = 393216 exact
    float w = Ws[i];
    unsigned short h = f2bf(w);
    Wh[i] = h;
    Wl[i] = f2bf(w - bf2f(h));
}

__global__ __launch_bounds__(512)
__attribute__((amdgpu_waves_per_eu(2, 2)))   // 1 WG/CU (LDS-capped): let allocator use the full 256 V+A budget
void fused_mlp_som(const float* __restrict__ ctx_in,   // (4096, 2, 128, 128) f32
                   const float* __restrict__ bs,       // (6,256)
                   const float* __restrict__ Wout,     // (256)
                   const float* __restrict__ bout,     // (1)
                   const unsigned short* __restrict__ Wh,
                   const unsigned short* __restrict__ Wl,
                   float* __restrict__ out)            // (4096)
{
    extern __shared__ char smem[];
    float* ctxS   = (float*)smem;                 // [128][128] f32, swizzled (64 KB)
    float* entS   = ctxS + 128*128;               // [128][128] f32, swizzled (64 KB)
    float* inv_cn = entS + 128*128;               // [128]
    float* inv_en = inv_cn + 128;                 // [128]
    int*   idxm   = (int*)(inv_en + 128);         // [128]
    float* redbuf = (float*)(idxm + 128);         // [8]
    // Phase-2 aliases (after barrier): bf16 hi/lo x planes (128 KB over the fp32 tiles)
    unsigned short* xh = (unsigned short*)smem;   // [128][256]
    unsigned short* xl = xh + 128*256;            // [128][256], base offset 65536 B

    const int tid  = threadIdx.x;
    const int lane = tid & 63;
    const int bk   = blockIdx.x;

    // ---------------- stage ctx/ent -> LDS (swizzled float4 writes) ----------------
    const float4* gbase = (const float4*)(ctx_in + (size_t)bk * (2*128*128));
    #pragma unroll
    for (int it = 0; it < 8; ++it){
        int fi = tid + 512*it;           // 0..4095 float4s per 64KB tile
        int r  = fi >> 5;
        int c4 = fi & 31;
        float4 v = gbase[fi];
        *(float4*)&ctxS[FID4(r,c4)] = v;
        float4 e = gbase[fi + 4096];
        *(float4*)&entS[FID4(r,c4)] = e;
    }
    __syncthreads();

    // ---------------- row norms ----------------
    {
        int hf = tid & 1;
        int r  = (tid >> 1) & 127;
        const float* tile = (tid < 256) ? ctxS : entS;
        float s = 0.f;
        #pragma unroll
        for (int u = 0; u < 16; ++u){
            float4 v = *(const float4*)&tile[FID4(r, 16*hf + u)];
            s = fmaf(v.x, v.x, s); s = fmaf(v.y, v.y, s);
            s = fmaf(v.z, v.z, s); s = fmaf(v.w, v.w, s);
        }
        s += __shfl_xor(s, 1);
        if (hf == 0){
            float inv = 1.0f / sqrtf(s);
            if (tid < 256) inv_cn[r] = inv; else inv_en[r] = inv;
        }
    }
    __syncthreads();

    // ---------------- similarity (fp32 VALU, bit-stable ordering) + argmax ----------------
    {
        const int ti = tid >> 5;
        const int tj = tid & 31;
        const int l0 = ti * 8;
        float acc[8][4];
        #pragma unroll
        for (int i = 0; i < 8; ++i)
            #pragma unroll
            for (int j = 0; j < 4; ++j) acc[i][j] = 0.f;

        for (int kc = 0; kc < 32; ++kc){
            float4 e0 = *(const float4*)&entS[FID4(tj     , kc)];
            float4 e1 = *(const float4*)&entS[FID4(tj + 32, kc)];
            float4 e2 = *(const float4*)&entS[FID4(tj + 64, kc)];
            float4 e3 = *(const float4*)&entS[FID4(tj + 96, kc)];
            #pragma unroll
            for (int i = 0; i < 8; ++i){
                float4 a = *(const float4*)&ctxS[FID4(l0+i, kc)];
                acc[i][0] = fmaf(a.x,e0.x,acc[i][0]); acc[i][0] = fmaf(a.y,e0.y,acc[i][0]);
                acc[i][0] = fmaf(a.z,e0.z,acc[i][0]); acc[i][0] = fmaf(a.w,e0.w,acc[i][0]);
                acc[i][1] = fmaf(a.x,e1.x,acc[i][1]); acc[i][1] = fmaf(a.y,e1.y,acc[i][1]);
                acc[i][1] = fmaf(a.z,e1.z,acc[i][1]); acc[i][1] = fmaf(a.w,e1.w,acc[i][1]);
                acc[i][2] = fmaf(a.x,e2.x,acc[i][2]); acc[i][2] = fmaf(a.y,e2.y,acc[i][2]);
                acc[i][2] = fmaf(a.z,e2.z,acc[i][2]); acc[i][2] = fmaf(a.w,e2.w,acc[i][2]);
                acc[i][3] = fmaf(a.x,e3.x,acc[i][3]); acc[i][3] = fmaf(a.y,e3.y,acc[i][3]);
                acc[i][3] = fmaf(a.z,e3.z,acc[i][3]); acc[i][3] = fmaf(a.w,e3.w,acc[i][3]);
            }
        }
        #pragma unroll
        for (int i = 0; i < 8; ++i){
            float best = -1e38f; int bi = 0;
            #pragma unroll
            for (int j = 0; j < 4; ++j){
                int m = tj + 32*j;
                float v = acc[i][j] * inv_en[m];
                if (v > best || (v == best && m < bi)){ best = v; bi = m; }
            }
            #pragma unroll
            for (int s = 1; s < 32; s <<= 1){
                float ov = __shfl_xor(best, s);
                int   oi = __shfl_xor(bi,   s);
                if (ov > best || (ov == best && oi < bi)){ best = ov; bi = oi; }
            }
            if (tj == 0) idxm[l0 + i] = bi;
        }
    }
    __syncthreads();

    // ---------------- build x0 = [ctx_n | ent_n[idx]] bf16 hi/lo, XOR-swizzled (&7 on xf) ----------------
    {
        const int c    = tid & 255;
        const int half = tid >> 8;
        unsigned pk[64];
        #pragma unroll
        for (int r = 0; r < 64; ++r){
            int l = half*64 + r;
            float v;
            if (c < 128){
                v = ctxS[FIDS(l, c)] * inv_cn[l];
            } else {
                int mi = idxm[l];
                v = entS[FIDS(mi, c-128)] * inv_en[mi];
            }
            unsigned short h  = f2bf(v);
            unsigned short lo = f2bf(v - bf2f(h));
            pk[r] = (unsigned)h | ((unsigned)lo << 16);
        }
        __syncthreads();
        #pragma unroll
        for (int r = 0; r < 64; ++r){
            int l  = half*64 + r;
            int ci = (((2*c) ^ ((l & 7) << 4)) >> 1);
            xh[l*256 + ci] = (unsigned short)(pk[r] & 0xffffu);
            xl[l*256 + ci] = (unsigned short)(pk[r] >> 16);
        }
    }
    __syncthreads();

    // ---------------- 6-layer MLP: bf16 3-product MFMA, ONE acc set (64 AGPRs) ----------------
    // Products: xh*Wh + xh*Wl + xl*Wh  (xl*Wl ~2^-16, dropped). All accumulate into acc.
    // N-split-8: wave wv owns output cols [32wv, 32wv+32).
    const int wv    = tid >> 6;
    const int lan15 = lane & 15;
    const int lq    = lane >> 4;
    const int n0    = 32*wv + lan15;
    const int n1    = n0 + 16;
    const int bno0  = n0 * 256;
    const int bno1  = n1 * 256;
    const int kb    = 8*lq;
    const int aBase = lan15*256;          // + mt*4096 + aoff; xl adds 32768 (fits 16-bit imm)
    const int amask = (lan15 & 7) << 4;

    // B-frag state hoisted ACROSS layers: prefetch crosses the layer barrier.
    bf16x8 bh0 = *(const bf16x8*)&Wh[bno0 + kb];
    bf16x8 bl0 = *(const bf16x8*)&Wl[bno0 + kb];
    bf16x8 bh1 = *(const bf16x8*)&Wh[bno1 + kb];
    bf16x8 bl1 = *(const bf16x8*)&Wl[bno1 + kb];

    #pragma unroll 1
    for (int layer = 0; layer < 6; ++layer){
        const unsigned short* WhL = Wh + layer*65536;
        const unsigned short* WlL = Wl + layer*65536;
        const int nlay = (layer < 5) ? (layer+1) : 5;
        const unsigned short* WhN = Wh + nlay*65536;
        const unsigned short* WlN = Wl + nlay*65536;

        f32x4 acc[8][2];
        #pragma unroll
        for (int mt = 0; mt < 8; ++mt){
            acc[mt][0] = (f32x4){0.f,0.f,0.f,0.f};
            acc[mt][1] = (f32x4){0.f,0.f,0.f,0.f};
        }

        #pragma unroll 1
        for (int ks = 0; ks < 8; ++ks){
            // batched A-frag reads: ONE vaddr + 16 imm offsets (mt*4096, +32768 for xl)
            const int aoff = (((64*ks + 16*lq) ^ amask) >> 1);
            bf16x8 ah_[8], al_[8];
            #pragma unroll
            for (int mt = 0; mt < 8; ++mt){
                ah_[mt] = *(const bf16x8*)&xh[aBase + mt*4096 + aoff];
                al_[mt] = *(const bf16x8*)&xl[aBase + mt*4096 + aoff];
            }
            // prefetch next-ks B frags; at ks==7 prefetch NEXT LAYER's first frags
            const unsigned short* pWh = (ks < 7) ? WhL : WhN;
            const unsigned short* pWl = (ks < 7) ? WlL : WlN;
            const int kn = (ks < 7) ? (32*(ks+1) + kb) : kb;
            bf16x8 nh0 = *(const bf16x8*)&pWh[bno0 + kn];
            bf16x8 nl0 = *(const bf16x8*)&pWl[bno0 + kn];
            bf16x8 nh1 = *(const bf16x8*)&pWh[bno1 + kn];
            bf16x8 nl1 = *(const bf16x8*)&pWl[bno1 + kn];
            #pragma unroll
            for (int mt = 0; mt < 8; ++mt){
                acc[mt][0] = __builtin_amdgcn_mfma_f32_16x16x32_bf16(ah_[mt], bh0, acc[mt][0], 0,0,0);
                acc[mt][1] = __builtin_amdgcn_mfma_f32_16x16x32_bf16(ah_[mt], bh1, acc[mt][1], 0,0,0);
                acc[mt][0] = __builtin_amdgcn_mfma_f32_16x16x32_bf16(ah_[mt], bl0, acc[mt][0], 0,0,0);
                acc[mt][1] = __builtin_amdgcn_mfma_f32_16x16x32_bf16(ah_[mt], bl1, acc[mt][1], 0,0,0);
                acc[mt][0] = __builtin_amdgcn_mfma_f32_16x16x32_bf16(al_[mt], bh0, acc[mt][0], 0,0,0);
                acc[mt][1] = __builtin_amdgcn_mfma_f32_16x16x32_bf16(al_[mt], bh1, acc[mt][1], 0,0,0);
            }
            bh0 = nh0; bl0 = nl0; bh1 = nh1; bl1 = nl1;
        }
        __syncthreads();   // all waves done reading xh/xl (next-layer B loads stay in flight)

        if (layer < 5){
            float bias0 = bs[layer*256 + n0];
            float bias1 = bs[layer*256 + n1];
            #pragma unroll
            for (int mt = 0; mt < 8; ++mt){
                #pragma unroll
                for (int r = 0; r < 4; ++r){
                    int row = 16*mt + 4*lq + r;      // C/D: col=lane&15, row=(lane>>4)*4+reg
                    int sw  = (row & 7) << 4;
                    float t0 = tanh_fast(acc[mt][0][r] + bias0);
                    float t1 = tanh_fast(acc[mt][1][r] + bias1);
                    unsigned short h0 = f2bf(t0);
                    unsigned short o0 = f2bf(t0 - bf2f(h0));
                    unsigned short h1 = f2bf(t1);
                    unsigned short o1 = f2bf(t1 - bf2f(h1));
                    int ci0 = (((2*n0) ^ sw) >> 1);
                    int ci1 = (((2*n1) ^ sw) >> 1);
                    xh[row*256 + ci0] = h0;  xl[row*256 + ci0] = o0;
                    xh[row*256 + ci1] = h1;  xl[row*256 + ci1] = o1;
                }
            }
            __syncthreads();
        } else {
            float bias0 = bs[5*256 + n0];
            float bias1 = bs[5*256 + n1];
            float w0 = Wout[n0];
            float w1 = Wout[n1];
            float part = 0.f;
            #pragma unroll
            for (int mt = 0; mt < 8; ++mt){
                #pragma unroll
                for (int r = 0; r < 4; ++r){
                    part = fmaf(tanh_fast(acc[mt][0][r] + bias0), w0, part);
                    part = fmaf(tanh_fast(acc[mt][1][r] + bias1), w1, part);
                }
            }
            #pragma unroll
            for (int s = 1; s < 64; s <<= 1) part += __shfl_xor(part, s);
            if (lane == 0) redbuf[wv] = part;
            __syncthreads();
            if (tid == 0){
                float s = 0.f;
                #pragma unroll
                for (int i = 0; i < 8; ++i) s += redbuf[i];
                out[bk] = s + 128.0f * bout[0];
            }
        }
    }
}

extern "C" void kernel_launch(void* const* d_in, const int* in_sizes, int n_in,
                              void* d_out, int out_size, void* d_ws, size_t ws_size,
                              hipStream_t stream)
{
    (void)in_sizes; (void)n_in; (void)out_size; (void)ws_size;
    const float* ctx  = (const float*)d_in[0];
    const float* Ws   = (const float*)d_in[1];
    const float* bs   = (const float*)d_in[2];
    const float* Wout = (const float*)d_in[3];
    const float* bout = (const float*)d_in[4];
    float* out = (float*)d_out;

    unsigned short* Wh = (unsigned short*)d_ws;          // 6*256*256 bf16 hi plane
    unsigned short* Wl = Wh + 6*256*256;                 // lo plane (1.5 MB total)

    pack_w_kernel<<<dim3(1536), dim3(256), 0, stream>>>(Ws, Wh, Wl);

    const int smem_bytes = 2*128*128*4 + 128*4 + 128*4 + 128*4 + 8*4;  // 132640 B
    hipFuncSetAttribute(reinterpret_cast<const void*>(fused_mlp_som),
                        hipFuncAttributeMaxDynamicSharedMemorySize, smem_bytes);
    fused_mlp_som<<<dim3(4096), dim3(512), smem_bytes, stream>>>(ctx, bs, Wout, bout, Wh, Wl, out);
}

// Round 6
// 1615.975 us; speedup vs baseline: 1.1163x; 1.1163x over previous
//
#include <hip/hip_runtime.h>

// B=64,K=64 -> 4096 (b,k) blocks; L=128 rows; D=128; H=256; 6 layers.
// Phase-1 fp32 tiles XOR-swizzled on 16B chunks: chunk' = chunk ^ (row&31)
#define FID4(r,c4) ((r)*128 + ((((c4) ^ ((r)&31))) << 2))               // float4 chunk addr (dwords)
#define FIDS(r,c)  ((r)*128 + (((((c)>>2) ^ ((r)&31))) << 2) + ((c)&3))  // scalar float addr
// Phase-2 fp16 x-buffer [128][256], swizzled on 8-elem (16B) chunks (R3-validated)
#define XIDX(r,c)  ((r)*256 + (((((c)>>3) ^ ((r)&7))) << 3) + ((c)&7))

typedef _Float16 half_t;
typedef __attribute__((ext_vector_type(8))) _Float16 f16x8;
typedef __attribute__((ext_vector_type(4))) float f32x4;

__device__ __forceinline__ float tanh_fast(float x){
    float e = __expf(2.0f * x);
    return 1.0f - 2.0f / (e + 1.0f);
}

// 8 fp32 -> f16x8 (RNE, identical to the former pack kernel's conversion)
__device__ __forceinline__ f16x8 cvt8(float4 a, float4 b){
    f16x8 r;
    r[0]=(half_t)a.x; r[1]=(half_t)a.y; r[2]=(half_t)a.z; r[3]=(half_t)a.w;
    r[4]=(half_t)b.x; r[5]=(half_t)b.y; r[6]=(half_t)b.z; r[7]=(half_t)b.w;
    return r;
}

// Single kernel, no workspace, no inter-kernel dependency (R5 tripwire fix).
__global__ __launch_bounds__(512)
__attribute__((amdgpu_waves_per_eu(2, 2)))   // R3's exact (passing) occupancy config
void fused_mlp_som(const float* __restrict__ ctx_in,   // (4096, 2, 128, 128) f32
                   const float* __restrict__ Ws,       // (6,256,256) f32
                   const float* __restrict__ bs,       // (6,256)
                   const float* __restrict__ Wout,     // (256)
                   const float* __restrict__ bout,     // (1)
                   float* __restrict__ out)            // (4096)
{
    extern __shared__ char smem[];
    float* ctxS   = (float*)smem;                 // [128][128] f32, swizzled (64 KB)
    float* entS   = ctxS + 128*128;               // [128][128] f32, swizzled (64 KB)
    float* inv_cn = entS + 128*128;               // [128]
    float* inv_en = inv_cn + 128;                 // [128]
    int*   idxm   = (int*)(inv_en + 128);         // [128]
    float* redbuf = (float*)(idxm + 128);         // [8]
    // Phase-2 alias (after barrier): fp16 x-buffer [128][256] = 64 KB over ctxS
    half_t* xf = (half_t*)smem;

    const int tid  = threadIdx.x;
    const int lane = tid & 63;
    const int bk   = blockIdx.x;

    // ---------------- stage ctx/ent -> LDS (swizzled float4 writes) ----------------
    const float4* gbase = (const float4*)(ctx_in + (size_t)bk * (2*128*128));
    #pragma unroll
    for (int it = 0; it < 8; ++it){
        int fi = tid + 512*it;           // 0..4095 float4s per 64KB tile
        int r  = fi >> 5;
        int c4 = fi & 31;
        float4 v = gbase[fi];
        *(float4*)&ctxS[FID4(r,c4)] = v;
        float4 e = gbase[fi + 4096];
        *(float4*)&entS[FID4(r,c4)] = e;
    }
    __syncthreads();

    // ---------------- row norms (bit-identical across rounds) ----------------
    {
        int hf = tid & 1;
        int r  = (tid >> 1) & 127;
        const float* tile = (tid < 256) ? ctxS : entS;
        float s = 0.f;
        #pragma unroll
        for (int u = 0; u < 16; ++u){
            float4 v = *(const float4*)&tile[FID4(r, 16*hf + u)];
            s = fmaf(v.x, v.x, s); s = fmaf(v.y, v.y, s);
            s = fmaf(v.z, v.z, s); s = fmaf(v.w, v.w, s);
        }
        s += __shfl_xor(s, 1);
        if (hf == 0){
            float inv = 1.0f / sqrtf(s);
            if (tid < 256) inv_cn[r] = inv; else inv_en[r] = inv;
        }
    }
    __syncthreads();

    // ---------------- similarity (fp32 VALU, R1-R4 bit order) + argmax ----------------
    {
        const int ti = tid >> 5;
        const int tj = tid & 31;
        const int l0 = ti * 8;
        float acc[8][4];
        #pragma unroll
        for (int i = 0; i < 8; ++i)
            #pragma unroll
            for (int j = 0; j < 4; ++j) acc[i][j] = 0.f;

        for (int kc = 0; kc < 32; ++kc){
            float4 e0 = *(const float4*)&entS[FID4(tj     , kc)];
            float4 e1 = *(const float4*)&entS[FID4(tj + 32, kc)];
            float4 e2 = *(const float4*)&entS[FID4(tj + 64, kc)];
            float4 e3 = *(const float4*)&entS[FID4(tj + 96, kc)];
            #pragma unroll
            for (int i = 0; i < 8; ++i){
                float4 a = *(const float4*)&ctxS[FID4(l0+i, kc)];
                acc[i][0] = fmaf(a.x,e0.x,acc[i][0]); acc[i][0] = fmaf(a.y,e0.y,acc[i][0]);
                acc[i][0] = fmaf(a.z,e0.z,acc[i][0]); acc[i][0] = fmaf(a.w,e0.w,acc[i][0]);
                acc[i][1] = fmaf(a.x,e1.x,acc[i][1]); acc[i][1] = fmaf(a.y,e1.y,acc[i][1]);
                acc[i][1] = fmaf(a.z,e1.z,acc[i][1]); acc[i][1] = fmaf(a.w,e1.w,acc[i][1]);
                acc[i][2] = fmaf(a.x,e2.x,acc[i][2]); acc[i][2] = fmaf(a.y,e2.y,acc[i][2]);
                acc[i][2] = fmaf(a.z,e2.z,acc[i][2]); acc[i][2] = fmaf(a.w,e2.w,acc[i][2]);
                acc[i][3] = fmaf(a.x,e3.x,acc[i][3]); acc[i][3] = fmaf(a.y,e3.y,acc[i][3]);
                acc[i][3] = fmaf(a.z,e3.z,acc[i][3]); acc[i][3] = fmaf(a.w,e3.w,acc[i][3]);
            }
        }
        #pragma unroll
        for (int i = 0; i < 8; ++i){
            float best = -1e38f; int bi = 0;
            #pragma unroll
            for (int j = 0; j < 4; ++j){
                int m = tj + 32*j;
                float v = acc[i][j] * inv_en[m];
                if (v > best || (v == best && m < bi)){ best = v; bi = m; }
            }
            #pragma unroll
            for (int s = 1; s < 32; s <<= 1){
                float ov = __shfl_xor(best, s);
                int   oi = __shfl_xor(bi,   s);
                if (ov > best || (ov == best && oi < bi)){ best = ov; bi = oi; }
            }
            if (tj == 0) idxm[l0 + i] = bi;
        }
    }
    __syncthreads();

    // ---------------- build x0 = [ctx_n | ent_n[idx]] as fp16, XOR-swizzled ----------------
    {
        const int c  = tid & 255;
        const int hb = tid >> 8;
        half_t pk[64];
        #pragma unroll
        for (int r = 0; r < 64; ++r){
            int l = hb*64 + r;
            float v;
            if (c < 128){
                v = ctxS[FIDS(l, c)] * inv_cn[l];
            } else {
                int mi = idxm[l];
                v = entS[FIDS(mi, c-128)] * inv_en[mi];
            }
            pk[r] = (half_t)v;
        }
        __syncthreads();
        #pragma unroll
        for (int r = 0; r < 64; ++r){
            int l = hb*64 + r;
            xf[XIDX(l, c)] = pk[r];
        }
    }
    __syncthreads();

    // ---------------- 6-layer MLP: fp16 single-product MFMA, W converted inline ----------------
    // N-split-8: wave wv owns output cols [32wv, 32wv+32).
    const int wv    = tid >> 6;
    const int lan15 = lane & 15;
    const int lq    = lane >> 4;
    const int n0    = 32*wv + lan15;
    const int n1    = n0 + 16;
    const int bno0  = n0 * 256;
    const int bno1  = n1 * 256;
    const int kb    = 8*lq;

    // raw fp32 W prefetch state, carried across layers (converted to fp16 at use)
    float4 p0a = *(const float4*)&Ws[bno0 + kb];
    float4 p0b = *(const float4*)&Ws[bno0 + kb + 4];
    float4 p1a = *(const float4*)&Ws[bno1 + kb];
    float4 p1b = *(const float4*)&Ws[bno1 + kb + 4];

    #pragma unroll 1
    for (int layer = 0; layer < 6; ++layer){
        const float* WsL = Ws + layer*65536;
        const float* WsN = Ws + ((layer < 5) ? (layer+1) : 5)*65536;

        f32x4 acc[8][2];
        #pragma unroll
        for (int mt = 0; mt < 8; ++mt){
            acc[mt][0] = (f32x4){0.f,0.f,0.f,0.f};
            acc[mt][1] = (f32x4){0.f,0.f,0.f,0.f};
        }

        #pragma unroll 1
        for (int ks = 0; ks < 8; ++ks){
            // batched A-frag reads: one vaddr + 8 imm offsets (mt*4096 halfs = 8192 B)
            const int aoff = (((4*ks + lq) ^ (lan15 & 7)) << 3);
            f16x8 a[8];
            #pragma unroll
            for (int mt = 0; mt < 8; ++mt)
                a[mt] = *(const f16x8*)&xf[(16*mt + lan15)*256 + aoff];
            // convert this ks's B frags from the prefetched fp32
            f16x8 b0 = cvt8(p0a, p0b);
            f16x8 b1 = cvt8(p1a, p1b);
            // prefetch next ks (at ks==7: next layer's first frags) — raw fp32
            const float* pW = (ks < 7) ? WsL : WsN;
            const int kn = (ks < 7) ? (32*(ks+1) + kb) : kb;
            p0a = *(const float4*)&pW[bno0 + kn];
            p0b = *(const float4*)&pW[bno0 + kn + 4];
            p1a = *(const float4*)&pW[bno1 + kn];
            p1b = *(const float4*)&pW[bno1 + kn + 4];
            #pragma unroll
            for (int mt = 0; mt < 8; ++mt){
                acc[mt][0] = __builtin_amdgcn_mfma_f32_16x16x32_f16(a[mt], b0, acc[mt][0], 0,0,0);
                acc[mt][1] = __builtin_amdgcn_mfma_f32_16x16x32_f16(a[mt], b1, acc[mt][1], 0,0,0);
            }
        }
        __syncthreads();   // all waves done reading xf (next-layer W loads stay in flight)

        if (layer < 5){
            float bias0 = bs[layer*256 + n0];
            float bias1 = bs[layer*256 + n1];
            #pragma unroll
            for (int mt = 0; mt < 8; ++mt){
                #pragma unroll
                for (int r = 0; r < 4; ++r){
                    int row = 16*mt + 4*lq + r;      // C/D: col=lane&15, row=(lane>>4)*4+reg
                    xf[XIDX(row, n0)] = (half_t)tanh_fast(acc[mt][0][r] + bias0);
                    xf[XIDX(row, n1)] = (half_t)tanh_fast(acc[mt][1][r] + bias1);
                }
            }
            __syncthreads();
        } else {
            float bias0 = bs[5*256 + n0];
            float bias1 = bs[5*256 + n1];
            float w0 = Wout[n0];
            float w1 = Wout[n1];
            float part = 0.f;
            #pragma unroll
            for (int mt = 0; mt < 8; ++mt){
                #pragma unroll
                for (int r = 0; r < 4; ++r){
                    part = fmaf(tanh_fast(acc[mt][0][r] + bias0), w0, part);
                    part = fmaf(tanh_fast(acc[mt][1][r] + bias1), w1, part);
                }
            }
            #pragma unroll
            for (int s = 1; s < 64; s <<= 1) part += __shfl_xor(part, s);
            if (lane == 0) redbuf[wv] = part;
            __syncthreads();
            if (tid == 0){
                float s = 0.f;
                #pragma unroll
                for (int i = 0; i < 8; ++i) s += redbuf[i];
                out[bk] = s + 128.0f * bout[0];
            }
        }
    }
}

extern "C" void kernel_launch(void* const* d_in, const int* in_sizes, int n_in,
                              void* d_out, int out_size, void* d_ws, size_t ws_size,
                              hipStream_t stream)
{
    (void)in_sizes; (void)n_in; (void)out_size; (void)d_ws; (void)ws_size;
    const float* ctx  = (const float*)d_in[0];
    const float* Ws   = (const float*)d_in[1];
    const float* bs   = (const float*)d_in[2];
    const float* Wout = (const float*)d_in[3];
    const float* bout = (const float*)d_in[4];
    float* out = (float*)d_out;

    const int smem_bytes = 2*128*128*4 + 128*4 + 128*4 + 128*4 + 8*4;  // 132640 B
    hipFuncSetAttribute(reinterpret_cast<const void*>(fused_mlp_som),
                        hipFuncAttributeMaxDynamicSharedMemorySize, smem_bytes);
    fused_mlp_som<<<dim3(4096), dim3(512), smem_bytes, stream>>>(ctx, Ws, bs, Wout, bout, out);
}